// Round 8
// baseline (320.265 us; speedup 1.0000x reference)
//
#include <hip/hip_runtime.h>
#include <hip/hip_bf16.h>

#define H  1024
#define S  32768
#define H2 2048
#define H3 3072

typedef __attribute__((ext_vector_type(8)))  short bf16x8;   // 8 bf16 = 4 VGPRs
typedef __attribute__((ext_vector_type(4)))  float f32x4;    // 16x16 MFMA C/D frag
typedef __attribute__((ext_vector_type(16))) float f32x16;   // 32x32 MFMA C/D frag

// ---------- fp32 -> bf16 (RNE) helpers ----------
__device__ __forceinline__ unsigned short f2bf(float f) {
    unsigned u = __float_as_uint(f);
    u += 0x7fffu + ((u >> 16) & 1u);
    return (unsigned short)(u >> 16);
}

__device__ __forceinline__ unsigned cvt_pk(float lo, float hi) {
    __hip_bfloat162 h = __float22bfloat162_rn(make_float2(lo, hi));
    unsigned u;
    __builtin_memcpy(&u, &h, 4);
    return u;
}

// fast tanh via v_exp_f32: tanh(x) = 1 - 2/(e^(2x)+1)
__device__ __forceinline__ float tanh_fast(float x) {
    float e = __expf(2.0f * x);
    return 1.0f - 2.0f / (e + 1.0f);
}

// ---------- async global->LDS 16B ----------
__device__ __forceinline__ void async_copy16(const void* g, void* l) {
    __builtin_amdgcn_global_load_lds(
        (const __attribute__((address_space(1))) unsigned int*)g,
        (__attribute__((address_space(3))) unsigned int*)l,
        16, 0, 0);
}

// ---------- fused prep: zero logits, enc->bf16 (fast path), W2->bf16, dvec ----------
// grid = 32 [+32768 if do_enc] + 1024 + 256
__global__ void prep_all(const float* __restrict__ enc, const float* __restrict__ attn_w,
                         const float* __restrict__ attn_b, const float* __restrict__ hidden,
                         unsigned short* __restrict__ ebf, unsigned short* __restrict__ w2b,
                         float* __restrict__ dvec, float* __restrict__ logits, int do_enc) {
    int b = blockIdx.x;
    if (b < 32) {
        ((float4*)logits)[b * 256 + threadIdx.x] = (float4){0.f, 0.f, 0.f, 0.f};
        return;
    }
    b -= 32;
    if (do_enc) {
        if (b < 32768) {
            size_t idx4 = (size_t)b * 256 + threadIdx.x;       // float4 chunk id
            float4 f = ((const float4*)enc)[idx4];
            ushort4 u;
            u.x = f2bf(f.x); u.y = f2bf(f.y); u.z = f2bf(f.z); u.w = f2bf(f.w);
            ((ushort4*)ebf)[idx4] = u;
            return;
        }
        b -= 32768;
    }
    if (b < 1024) {
        // W2 = attn_w[:, 2048:3072] -> bf16 row-major (N=1024 x K=1024)
        int idx4 = b * 256 + threadIdx.x;
        int n = idx4 >> 8;
        int c = (idx4 & 255) * 4;
        float4 f = *(const float4*)(attn_w + (size_t)n * H3 + H2 + c);
        ushort4 u;
        u.x = f2bf(f.x); u.y = f2bf(f.y); u.z = f2bf(f.z); u.w = f2bf(f.w);
        *(ushort4*)(w2b + (size_t)n * H + c) = u;
        return;
    }
    // dvec[i] = attn_b[i] + sum_{k<2048} hidden[k]*attn_w[i][k]
    b -= 1024;
    int wv = threadIdx.x >> 6, lane = threadIdx.x & 63;
    int row = b * 4 + wv;
    const float* wrow = attn_w + (size_t)row * H3;
    float s = 0.f;
    #pragma unroll
    for (int j = 0; j < 32; ++j) {
        int k = lane + j * 64;
        s += wrow[k] * hidden[k];
    }
    #pragma unroll
    for (int m = 1; m <= 32; m <<= 1) s += __shfl_xor(s, m);
    if (lane == 0) dvec[row] = s + attn_b[row];
}

// ---------- FAST gemm: BK=128, 32x32x16 MFMA, XOR-swizzled LDS, global_load_lds ----------
// tile BM=128 BN=128 BK=128; 256 threads (2x2 waves, 64x64/wave); 8 k-iterations.
// Grid decode rowBlock = blockIdx&255 (XCD-affine: all 8 colBlock sharers of an
// A-tile land on one XCD -> round-7 verified FETCH drop vs colBlock-fastest).
// LDS row = 256 B = 16 chunks of 16 B; chunk c (c=p*256+tid): row=c>>4,
// slot=c&15 holds global k-chunk (slot ^ (row&15)) -> consumer slot
// (2s+half)^(row&15); per-instruction bank load uniform (8 lanes/bank-group).
// 32x32x16 frags: A[m=lane&31][k=(lane>>5)*8+j]; C/D col=lane&31,
// row=(reg&3)+8*(reg>>2)+4*(lane>>5)  [m74/m101-verified mapping].
__global__ __launch_bounds__(256, 2) void attn_gemm_fast(
        const unsigned short* __restrict__ ebf, const unsigned short* __restrict__ w2b,
        const float* __restrict__ dvec, const float* __restrict__ vw,
        float* __restrict__ logits) {
    __shared__ unsigned short Atile[128 * 128];   // 32 KB
    __shared__ unsigned short Btile[128 * 128];   // 32 KB

    const int tid = threadIdx.x;
    const int rowBlock = blockIdx.x & 255;        // XCD-affine
    const int colBlock = blockIdx.x >> 8;         // 0..7

    const int lane = tid & 63;
    const int wv = tid >> 6;
    const int waveM = wv >> 1, waveN = wv & 1;
    const int l32 = lane & 31, half = lane >> 5;

    f32x16 acc[2][2];
    #pragma unroll
    for (int mi = 0; mi < 2; ++mi)
        #pragma unroll
        for (int ni = 0; ni < 2; ++ni)
            #pragma unroll
            for (int r = 0; r < 16; ++r)
                acc[mi][ni][r] = 0.f;

    const size_t aRow0 = (size_t)(rowBlock * 128) * H;
    const size_t bRow0 = (size_t)(colBlock * 128) * H;

    // staging geometry: chunk c = p*256+tid -> row = 16p + (tid>>4), slot = tid&15,
    // global k-chunk j = (tid&15) ^ (tid>>4)  (constant per thread)
    const int trow = tid >> 4;                       // 0..15
    const int jchunk = (tid & 15) ^ trow;
    const size_t gOff = (size_t)trow * H + jchunk * 8;

    for (int kt = 0; kt < 8; ++kt) {
        const int k0 = kt * 128;

        #pragma unroll
        for (int p = 0; p < 8; ++p)
            async_copy16(ebf + aRow0 + gOff + (size_t)p * 16 * H + k0,
                         (char*)Atile + (size_t)(p * 256 + tid) * 16);
        #pragma unroll
        for (int p = 0; p < 8; ++p)
            async_copy16(w2b + bRow0 + gOff + (size_t)p * 16 * H + k0,
                         (char*)Btile + (size_t)(p * 256 + tid) * 16);

        __syncthreads();   // compiler drains vmcnt(0) before s_barrier

        #pragma unroll
        for (int s = 0; s < 8; ++s) {             // 8 K=16 steps = BK 128
            bf16x8 af[2], bfr[2];
            #pragma unroll
            for (int i = 0; i < 2; ++i) {
                int ar = waveM * 64 + i * 32 + l32;
                int br = waveN * 64 + i * 32 + l32;
                int aslot = (2 * s + half) ^ (ar & 15);
                int bslot = (2 * s + half) ^ (br & 15);
                af[i]  = *(const bf16x8*)((const char*)Atile + ar * 256 + aslot * 16);
                bfr[i] = *(const bf16x8*)((const char*)Btile + br * 256 + bslot * 16);
            }
            #pragma unroll
            for (int mi = 0; mi < 2; ++mi)
                #pragma unroll
                for (int ni = 0; ni < 2; ++ni)
                    acc[mi][ni] = __builtin_amdgcn_mfma_f32_32x32x16_bf16(
                        af[mi], bfr[ni], acc[mi][ni], 0, 0, 0);
        }

        __syncthreads();   // tile consumed; next iter may overwrite
    }

    // ---- epilogue: logits[row] += sum_n tanh(acc + d[n]) * vw[n] ----
    float rowsum[2][16];
    #pragma unroll
    for (int mi = 0; mi < 2; ++mi)
        #pragma unroll
        for (int r = 0; r < 16; ++r) rowsum[mi][r] = 0.f;

    #pragma unroll
    for (int ni = 0; ni < 2; ++ni) {
        int n = colBlock * 128 + waveN * 64 + ni * 32 + l32;
        float dv = dvec[n];
        float vv = vw[n];
        #pragma unroll
        for (int mi = 0; mi < 2; ++mi)
            #pragma unroll
            for (int r = 0; r < 16; ++r)
                rowsum[mi][r] += tanh_fast(acc[mi][ni][r] + dv) * vv;
    }

    // reduce across the 32 lanes (l32) sharing each output row
    #pragma unroll
    for (int mi = 0; mi < 2; ++mi)
        #pragma unroll
        for (int r = 0; r < 16; ++r) {
            float s = rowsum[mi][r];
            s += __shfl_xor(s, 1);
            s += __shfl_xor(s, 2);
            s += __shfl_xor(s, 4);
            s += __shfl_xor(s, 8);
            s += __shfl_xor(s, 16);
            rowsum[mi][r] = s;
        }

    if (l32 == 0) {        // lanes 0 and 32 (different row sets via half)
        #pragma unroll
        for (int mi = 0; mi < 2; ++mi) {
            int rbase = rowBlock * 128 + waveM * 64 + mi * 32 + 4 * half;
            #pragma unroll
            for (int r = 0; r < 16; ++r)
                atomicAdd(&logits[rbase + (r & 3) + 8 * (r >> 2)], rowsum[mi][r]);
        }
    }
}

// ---------- FALLBACK gemm (small ws): BK=32, 16x16x32, inline fp32->bf16 A ----------
__global__ __launch_bounds__(256, 2) void attn_gemm_fb(
        const float* __restrict__ enc, const unsigned short* __restrict__ w2b,
        const float* __restrict__ dvec, const float* __restrict__ vw,
        float* __restrict__ logits) {
    __shared__ unsigned short Atile[128 * 32];
    __shared__ unsigned short Btile[128 * 32];

    const int tid = threadIdx.x;
    const int rowBlock = blockIdx.x & 255;
    const int colBlock = blockIdx.x >> 8;

    const int lane = tid & 63;
    const int wv = tid >> 6;
    const int waveM = wv >> 1, waveN = wv & 1;
    const int quad = lane >> 4, l16 = lane & 15;

    f32x4 acc[4][4];
    #pragma unroll
    for (int mi = 0; mi < 4; ++mi)
        #pragma unroll
        for (int ni = 0; ni < 4; ++ni)
            acc[mi][ni] = (f32x4){0.f, 0.f, 0.f, 0.f};

    const int arow = tid >> 3;
    const int akc  = (tid & 7) * 4;
    const size_t encRowBase = (size_t)(rowBlock * 128) * H;

    const unsigned short* Abase = Atile + (waveM * 64 + l16) * 32 + quad * 8;
    const unsigned short* Bbase = Btile + (waveN * 64 + l16) * 32 + quad * 8;

    for (int kt = 0; kt < 32; ++kt) {
        const int k0 = kt * 32;
        #pragma unroll
        for (int p = 0; p < 2; ++p) {
            int c = p * 256 + tid;
            int n = c >> 2, kk = (c & 3) * 8;
            async_copy16(w2b + (size_t)(colBlock * 128 + n) * H + k0 + kk,
                         (char*)Btile + (size_t)c * 16);
        }
        float4 av[4];
        #pragma unroll
        for (int p = 0; p < 4; ++p)
            av[p] = *(const float4*)(enc + encRowBase + (size_t)(arow + p * 32) * H + k0 + akc);
        #pragma unroll
        for (int p = 0; p < 4; ++p) {
            uint2 u;
            u.x = cvt_pk(av[p].x, av[p].y);
            u.y = cvt_pk(av[p].z, av[p].w);
            *(uint2*)(Atile + (arow + p * 32) * 32 + akc) = u;
        }

        __syncthreads();

        bf16x8 af[4], bfr[4];
        #pragma unroll
        for (int i = 0; i < 4; ++i) {
            af[i]  = *(const bf16x8*)(Abase + i * 16 * 32);
            bfr[i] = *(const bf16x8*)(Bbase + i * 16 * 32);
        }
        #pragma unroll
        for (int mi = 0; mi < 4; ++mi)
            #pragma unroll
            for (int ni = 0; ni < 4; ++ni)
                acc[mi][ni] = __builtin_amdgcn_mfma_f32_16x16x32_bf16(
                    af[mi], bfr[ni], acc[mi][ni], 0, 0, 0);

        __syncthreads();
    }

    // epilogue (16x16 C/D layout)
    float rowsum[4][4];
    #pragma unroll
    for (int mi = 0; mi < 4; ++mi)
        #pragma unroll
        for (int r = 0; r < 4; ++r) rowsum[mi][r] = 0.f;
    #pragma unroll
    for (int ni = 0; ni < 4; ++ni) {
        int colg = colBlock * 128 + waveN * 64 + ni * 16 + l16;
        float dv = dvec[colg];
        float vv = vw[colg];
        #pragma unroll
        for (int mi = 0; mi < 4; ++mi)
            #pragma unroll
            for (int r = 0; r < 4; ++r)
                rowsum[mi][r] += tanh_fast(acc[mi][ni][r] + dv) * vv;
    }
    #pragma unroll
    for (int mi = 0; mi < 4; ++mi)
        #pragma unroll
        for (int r = 0; r < 4; ++r) {
            float s = rowsum[mi][r];
            s += __shfl_xor(s, 1);
            s += __shfl_xor(s, 2);
            s += __shfl_xor(s, 4);
            s += __shfl_xor(s, 8);
            rowsum[mi][r] = s;
        }
    if (l16 == 0) {
        int rbase = rowBlock * 128 + waveM * 64 + quad * 4;
        #pragma unroll
        for (int mi = 0; mi < 4; ++mi)
            #pragma unroll
            for (int r = 0; r < 4; ++r)
                atomicAdd(&logits[rbase + mi * 16 + r], rowsum[mi][r]);
    }
}

// ---------- softmax over 32768 logits, single workgroup, in-place ----------
__global__ __launch_bounds__(1024) void softmax_k(float* __restrict__ x) {
    __shared__ float red[16];
    const int tid = threadIdx.x;
    const int lane = tid & 63, wv = tid >> 6;

    float v[32];
    float m = -1e30f;
    #pragma unroll
    for (int i = 0; i < 32; ++i) {
        v[i] = x[tid + (i << 10)];
        m = fmaxf(m, v[i]);
    }
    #pragma unroll
    for (int o = 1; o < 64; o <<= 1) m = fmaxf(m, __shfl_xor(m, o));
    if (lane == 0) red[wv] = m;
    __syncthreads();
    #pragma unroll
    for (int i = 0; i < 16; ++i) m = fmaxf(m, red[i]);
    __syncthreads();

    float s = 0.f;
    #pragma unroll
    for (int i = 0; i < 32; ++i) {
        v[i] = expf(v[i] - m);
        s += v[i];
    }
    #pragma unroll
    for (int o = 1; o < 64; o <<= 1) s += __shfl_xor(s, o);
    if (lane == 0) red[wv] = s;
    __syncthreads();
    float tot = 0.f;
    #pragma unroll
    for (int i = 0; i < 16; ++i) tot += red[i];
    float inv = 1.0f / tot;

    #pragma unroll
    for (int i = 0; i < 32; ++i) x[tid + (i << 10)] = v[i] * inv;
}

extern "C" void kernel_launch(void* const* d_in, const int* in_sizes, int n_in,
                              void* d_out, int out_size, void* d_ws, size_t ws_size,
                              hipStream_t stream) {
    const float* hidden = (const float*)d_in[0];   // (1, 2048)
    const float* enc    = (const float*)d_in[1];   // (32768, 1024)
    const float* attn_w = (const float*)d_in[2];   // (1024, 3072)
    const float* attn_b = (const float*)d_in[3];   // (1024,)
    const float* v_w    = (const float*)d_in[4];   // (1, 1024)
    float* out = (float*)d_out;                    // (32768,) fp32

    const size_t EBF_BYTES = (size_t)S * H * 2;    // 64 MB
    const size_t W2_BYTES  = (size_t)H * H * 2;    // 2 MB
    const bool fast = ws_size >= EBF_BYTES + W2_BYTES + 4096;

    if (fast) {
        unsigned short* ebf = (unsigned short*)d_ws;
        unsigned short* w2b = (unsigned short*)((char*)d_ws + EBF_BYTES);
        float* dvec = (float*)((char*)d_ws + EBF_BYTES + W2_BYTES);
        prep_all<<<dim3(32 + 32768 + 1024 + 256), dim3(256), 0, stream>>>(
            enc, attn_w, attn_b, hidden, ebf, w2b, dvec, out, 1);
        attn_gemm_fast<<<dim3(2048), dim3(256), 0, stream>>>(ebf, w2b, dvec, v_w, out);
    } else {
        unsigned short* w2b = (unsigned short*)d_ws;
        float* dvec = (float*)((char*)d_ws + W2_BYTES);
        prep_all<<<dim3(32 + 1024 + 256), dim3(256), 0, stream>>>(
            enc, attn_w, attn_b, hidden, nullptr, w2b, dvec, out, 0);
        attn_gemm_fb<<<dim3(2048), dim3(256), 0, stream>>>(enc, w2b, dvec, v_w, out);
    }
    softmax_k<<<dim3(1), dim3(1024), 0, stream>>>(out);
}

// Round 9
// 313.891 us; speedup vs baseline: 1.0203x; 1.0203x over previous
//
#include <hip/hip_runtime.h>
#include <hip/hip_bf16.h>

#define H  1024
#define S  32768
#define H2 2048
#define H3 3072

typedef __attribute__((ext_vector_type(8)))  short bf16x8;   // 8 bf16 = 4 VGPRs
typedef __attribute__((ext_vector_type(4)))  float f32x4;    // 16x16 MFMA C/D frag
typedef __attribute__((ext_vector_type(16))) float f32x16;   // 32x32 MFMA C/D frag

// ---------- fp32 -> bf16 (RNE) helpers ----------
__device__ __forceinline__ unsigned short f2bf(float f) {
    unsigned u = __float_as_uint(f);
    u += 0x7fffu + ((u >> 16) & 1u);
    return (unsigned short)(u >> 16);
}

__device__ __forceinline__ unsigned cvt_pk(float lo, float hi) {
    __hip_bfloat162 h = __float22bfloat162_rn(make_float2(lo, hi));
    unsigned u;
    __builtin_memcpy(&u, &h, 4);
    return u;
}

// fast tanh via v_exp_f32: tanh(x) = 1 - 2/(e^(2x)+1)
__device__ __forceinline__ float tanh_fast(float x) {
    float e = __expf(2.0f * x);
    return 1.0f - 2.0f / (e + 1.0f);
}

// ---------- async global->LDS 16B ----------
__device__ __forceinline__ void async_copy16(const void* g, void* l) {
    __builtin_amdgcn_global_load_lds(
        (const __attribute__((address_space(1))) unsigned int*)g,
        (__attribute__((address_space(3))) unsigned int*)l,
        16, 0, 0);
}

// ---------- fused prep: zero logits, enc->bf16 (fast path), W2->bf16, dvec ----------
// grid = 32 [+32768 if do_enc] + 1024 + 256
__global__ void prep_all(const float* __restrict__ enc, const float* __restrict__ attn_w,
                         const float* __restrict__ attn_b, const float* __restrict__ hidden,
                         unsigned short* __restrict__ ebf, unsigned short* __restrict__ w2b,
                         float* __restrict__ dvec, float* __restrict__ logits, int do_enc) {
    int b = blockIdx.x;
    if (b < 32) {
        ((float4*)logits)[b * 256 + threadIdx.x] = (float4){0.f, 0.f, 0.f, 0.f};
        return;
    }
    b -= 32;
    if (do_enc) {
        if (b < 32768) {
            size_t idx4 = (size_t)b * 256 + threadIdx.x;       // float4 chunk id
            float4 f = ((const float4*)enc)[idx4];
            ushort4 u;
            u.x = f2bf(f.x); u.y = f2bf(f.y); u.z = f2bf(f.z); u.w = f2bf(f.w);
            ((ushort4*)ebf)[idx4] = u;
            return;
        }
        b -= 32768;
    }
    if (b < 1024) {
        // W2 = attn_w[:, 2048:3072] -> bf16 row-major (N=1024 x K=1024)
        int idx4 = b * 256 + threadIdx.x;
        int n = idx4 >> 8;
        int c = (idx4 & 255) * 4;
        float4 f = *(const float4*)(attn_w + (size_t)n * H3 + H2 + c);
        ushort4 u;
        u.x = f2bf(f.x); u.y = f2bf(f.y); u.z = f2bf(f.z); u.w = f2bf(f.w);
        *(ushort4*)(w2b + (size_t)n * H + c) = u;
        return;
    }
    // dvec[i] = attn_b[i] + sum_{k<2048} hidden[k]*attn_w[i][k]
    b -= 1024;
    int wv = threadIdx.x >> 6, lane = threadIdx.x & 63;
    int row = b * 4 + wv;
    const float* wrow = attn_w + (size_t)row * H3;
    float s = 0.f;
    #pragma unroll
    for (int j = 0; j < 32; ++j) {
        int k = lane + j * 64;
        s += wrow[k] * hidden[k];
    }
    #pragma unroll
    for (int m = 1; m <= 32; m <<= 1) s += __shfl_xor(s, m);
    if (lane == 0) dvec[row] = s + attn_b[row];
}

// ---------- FAST gemm: BK=64 (round-7 LDS/occupancy), 32x32x16 MFMA ----------
// tile BM=128 BN=128 BK=64; 256 threads (2x2 waves, 64x64/wave); 16 k-iterations.
// LDS 2x16 KB -> ~3 blocks/CU residency (round-7 measured 35.6% occupancy;
// round-8's BK=128/64 KB capped at 2 blocks/CU and regressed — m132 pattern).
// Grid decode rowBlock = blockIdx&255 (XCD-affine; round-7 verified FETCH drop).
// LDS row = 128 B = 8 chunks of 16 B; slot j of row r holds global k-chunk
// j^(r&7) (swizzle applied on the GLOBAL source address; LDS dst stays
// lane-contiguous per global_load_lds rule). Consumer slot (2s+half)^(r&7):
// 8 lanes per 4-bank group per instruction = structural minimum (0 conflicts
// measured, rounds 4/7).
// 32x32x16 frags: A[m=lane&31][k=(lane>>5)*8+j]; C/D col=lane&31,
// row=(reg&3)+8*(reg>>2)+4*(lane>>5)  [m74/m101; round-8 correctness-verified].
__global__ __launch_bounds__(256, 2) void attn_gemm_fast(
        const unsigned short* __restrict__ ebf, const unsigned short* __restrict__ w2b,
        const float* __restrict__ dvec, const float* __restrict__ vw,
        float* __restrict__ logits) {
    __shared__ unsigned short Atile[128 * 64];   // 16 KB
    __shared__ unsigned short Btile[128 * 64];   // 16 KB

    const int tid = threadIdx.x;
    const int rowBlock = blockIdx.x & 255;        // XCD-affine
    const int colBlock = blockIdx.x >> 8;         // 0..7

    const int lane = tid & 63;
    const int wv = tid >> 6;
    const int waveM = wv >> 1, waveN = wv & 1;
    const int l32 = lane & 31, half = lane >> 5;

    f32x16 acc[2][2];
    #pragma unroll
    for (int mi = 0; mi < 2; ++mi)
        #pragma unroll
        for (int ni = 0; ni < 2; ++ni)
            #pragma unroll
            for (int r = 0; r < 16; ++r)
                acc[mi][ni][r] = 0.f;

    const size_t aRow0 = (size_t)(rowBlock * 128) * H;
    const size_t bRow0 = (size_t)(colBlock * 128) * H;

    // staging: 4 chunks per thread per operand; c = p*256+tid (0..1023)
    // row = c>>3, slot = c&7, global k-chunk = slot ^ (row&7)
    int srow[4], sk[4];
    #pragma unroll
    for (int p = 0; p < 4; ++p) {
        int c = p * 256 + tid;
        srow[p] = c >> 3;
        sk[p] = ((c & 7) ^ (srow[p] & 7)) * 8;   // element offset of swizzled chunk
    }

    for (int kt = 0; kt < 16; ++kt) {
        const int k0 = kt * 64;

        #pragma unroll
        for (int p = 0; p < 4; ++p) {
            int c = p * 256 + tid;
            async_copy16(ebf + aRow0 + (size_t)srow[p] * H + k0 + sk[p],
                         (char*)Atile + (size_t)c * 16);
        }
        #pragma unroll
        for (int p = 0; p < 4; ++p) {
            int c = p * 256 + tid;
            async_copy16(w2b + bRow0 + (size_t)srow[p] * H + k0 + sk[p],
                         (char*)Btile + (size_t)c * 16);
        }

        __syncthreads();   // compiler drains vmcnt(0) before s_barrier

        #pragma unroll
        for (int s = 0; s < 4; ++s) {             // 4 K=16 steps = BK 64
            bf16x8 af[2], bfr[2];
            #pragma unroll
            for (int i = 0; i < 2; ++i) {
                int ar = waveM * 64 + i * 32 + l32;
                int br = waveN * 64 + i * 32 + l32;
                int aslot = (2 * s + half) ^ (ar & 7);
                int bslot = (2 * s + half) ^ (br & 7);
                af[i]  = *(const bf16x8*)((const char*)Atile + ar * 128 + aslot * 16);
                bfr[i] = *(const bf16x8*)((const char*)Btile + br * 128 + bslot * 16);
            }
            #pragma unroll
            for (int mi = 0; mi < 2; ++mi)
                #pragma unroll
                for (int ni = 0; ni < 2; ++ni)
                    acc[mi][ni] = __builtin_amdgcn_mfma_f32_32x32x16_bf16(
                        af[mi], bfr[ni], acc[mi][ni], 0, 0, 0);
        }

        __syncthreads();   // tile consumed; next iter may overwrite
    }

    // ---- epilogue: logits[row] += sum_n tanh(acc + d[n]) * vw[n] ----
    float rowsum[2][16];
    #pragma unroll
    for (int mi = 0; mi < 2; ++mi)
        #pragma unroll
        for (int r = 0; r < 16; ++r) rowsum[mi][r] = 0.f;

    #pragma unroll
    for (int ni = 0; ni < 2; ++ni) {
        int n = colBlock * 128 + waveN * 64 + ni * 32 + l32;
        float dv = dvec[n];
        float vv = vw[n];
        #pragma unroll
        for (int mi = 0; mi < 2; ++mi)
            #pragma unroll
            for (int r = 0; r < 16; ++r)
                rowsum[mi][r] += tanh_fast(acc[mi][ni][r] + dv) * vv;
    }

    // reduce across the 32 lanes (l32) sharing each output row
    #pragma unroll
    for (int mi = 0; mi < 2; ++mi)
        #pragma unroll
        for (int r = 0; r < 16; ++r) {
            float s = rowsum[mi][r];
            s += __shfl_xor(s, 1);
            s += __shfl_xor(s, 2);
            s += __shfl_xor(s, 4);
            s += __shfl_xor(s, 8);
            s += __shfl_xor(s, 16);
            rowsum[mi][r] = s;
        }

    if (l32 == 0) {        // lanes 0 and 32 (different row sets via half)
        #pragma unroll
        for (int mi = 0; mi < 2; ++mi) {
            int rbase = rowBlock * 128 + waveM * 64 + mi * 32 + 4 * half;
            #pragma unroll
            for (int r = 0; r < 16; ++r)
                atomicAdd(&logits[rbase + (r & 3) + 8 * (r >> 2)], rowsum[mi][r]);
        }
    }
}

// ---------- FALLBACK gemm (small ws): BK=32, 16x16x32, inline fp32->bf16 A ----------
__global__ __launch_bounds__(256, 2) void attn_gemm_fb(
        const float* __restrict__ enc, const unsigned short* __restrict__ w2b,
        const float* __restrict__ dvec, const float* __restrict__ vw,
        float* __restrict__ logits) {
    __shared__ unsigned short Atile[128 * 32];
    __shared__ unsigned short Btile[128 * 32];

    const int tid = threadIdx.x;
    const int rowBlock = blockIdx.x & 255;
    const int colBlock = blockIdx.x >> 8;

    const int lane = tid & 63;
    const int wv = tid >> 6;
    const int waveM = wv >> 1, waveN = wv & 1;
    const int quad = lane >> 4, l16 = lane & 15;

    f32x4 acc[4][4];
    #pragma unroll
    for (int mi = 0; mi < 4; ++mi)
        #pragma unroll
        for (int ni = 0; ni < 4; ++ni)
            acc[mi][ni] = (f32x4){0.f, 0.f, 0.f, 0.f};

    const int arow = tid >> 3;
    const int akc  = (tid & 7) * 4;
    const size_t encRowBase = (size_t)(rowBlock * 128) * H;

    const unsigned short* Abase = Atile + (waveM * 64 + l16) * 32 + quad * 8;
    const unsigned short* Bbase = Btile + (waveN * 64 + l16) * 32 + quad * 8;

    for (int kt = 0; kt < 32; ++kt) {
        const int k0 = kt * 32;
        #pragma unroll
        for (int p = 0; p < 2; ++p) {
            int c = p * 256 + tid;
            int n = c >> 2, kk = (c & 3) * 8;
            async_copy16(w2b + (size_t)(colBlock * 128 + n) * H + k0 + kk,
                         (char*)Btile + (size_t)c * 16);
        }
        float4 av[4];
        #pragma unroll
        for (int p = 0; p < 4; ++p)
            av[p] = *(const float4*)(enc + encRowBase + (size_t)(arow + p * 32) * H + k0 + akc);
        #pragma unroll
        for (int p = 0; p < 4; ++p) {
            uint2 u;
            u.x = cvt_pk(av[p].x, av[p].y);
            u.y = cvt_pk(av[p].z, av[p].w);
            *(uint2*)(Atile + (arow + p * 32) * 32 + akc) = u;
        }

        __syncthreads();

        bf16x8 af[4], bfr[4];
        #pragma unroll
        for (int i = 0; i < 4; ++i) {
            af[i]  = *(const bf16x8*)(Abase + i * 16 * 32);
            bfr[i] = *(const bf16x8*)(Bbase + i * 16 * 32);
        }
        #pragma unroll
        for (int mi = 0; mi < 4; ++mi)
            #pragma unroll
            for (int ni = 0; ni < 4; ++ni)
                acc[mi][ni] = __builtin_amdgcn_mfma_f32_16x16x32_bf16(
                    af[mi], bfr[ni], acc[mi][ni], 0, 0, 0);

        __syncthreads();
    }

    // epilogue (16x16 C/D layout)
    float rowsum[4][4];
    #pragma unroll
    for (int mi = 0; mi < 4; ++mi)
        #pragma unroll
        for (int r = 0; r < 4; ++r) rowsum[mi][r] = 0.f;
    #pragma unroll
    for (int ni = 0; ni < 4; ++ni) {
        int colg = colBlock * 128 + waveN * 64 + ni * 16 + l16;
        float dv = dvec[colg];
        float vv = vw[colg];
        #pragma unroll
        for (int mi = 0; mi < 4; ++mi)
            #pragma unroll
            for (int r = 0; r < 4; ++r)
                rowsum[mi][r] += tanh_fast(acc[mi][ni][r] + dv) * vv;
    }
    #pragma unroll
    for (int mi = 0; mi < 4; ++mi)
        #pragma unroll
        for (int r = 0; r < 4; ++r) {
            float s = rowsum[mi][r];
            s += __shfl_xor(s, 1);
            s += __shfl_xor(s, 2);
            s += __shfl_xor(s, 4);
            s += __shfl_xor(s, 8);
            rowsum[mi][r] = s;
        }
    if (l16 == 0) {
        int rbase = rowBlock * 128 + waveM * 64 + quad * 4;
        #pragma unroll
        for (int mi = 0; mi < 4; ++mi)
            #pragma unroll
            for (int r = 0; r < 4; ++r)
                atomicAdd(&logits[rbase + mi * 16 + r], rowsum[mi][r]);
    }
}

// ---------- softmax over 32768 logits, single workgroup, in-place ----------
__global__ __launch_bounds__(1024) void softmax_k(float* __restrict__ x) {
    __shared__ float red[16];
    const int tid = threadIdx.x;
    const int lane = tid & 63, wv = tid >> 6;

    float v[32];
    float m = -1e30f;
    #pragma unroll
    for (int i = 0; i < 32; ++i) {
        v[i] = x[tid + (i << 10)];
        m = fmaxf(m, v[i]);
    }
    #pragma unroll
    for (int o = 1; o < 64; o <<= 1) m = fmaxf(m, __shfl_xor(m, o));
    if (lane == 0) red[wv] = m;
    __syncthreads();
    #pragma unroll
    for (int i = 0; i < 16; ++i) m = fmaxf(m, red[i]);
    __syncthreads();

    float s = 0.f;
    #pragma unroll
    for (int i = 0; i < 32; ++i) {
        v[i] = expf(v[i] - m);
        s += v[i];
    }
    #pragma unroll
    for (int o = 1; o < 64; o <<= 1) s += __shfl_xor(s, o);
    if (lane == 0) red[wv] = s;
    __syncthreads();
    float tot = 0.f;
    #pragma unroll
    for (int i = 0; i < 16; ++i) tot += red[i];
    float inv = 1.0f / tot;

    #pragma unroll
    for (int i = 0; i < 32; ++i) x[tid + (i << 10)] = v[i] * inv;
}

extern "C" void kernel_launch(void* const* d_in, const int* in_sizes, int n_in,
                              void* d_out, int out_size, void* d_ws, size_t ws_size,
                              hipStream_t stream) {
    const float* hidden = (const float*)d_in[0];   // (1, 2048)
    const float* enc    = (const float*)d_in[1];   // (32768, 1024)
    const float* attn_w = (const float*)d_in[2];   // (1024, 3072)
    const float* attn_b = (const float*)d_in[3];   // (1024,)
    const float* v_w    = (const float*)d_in[4];   // (1, 1024)
    float* out = (float*)d_out;                    // (32768,) fp32

    const size_t EBF_BYTES = (size_t)S * H * 2;    // 64 MB
    const size_t W2_BYTES  = (size_t)H * H * 2;    // 2 MB
    const bool fast = ws_size >= EBF_BYTES + W2_BYTES + 4096;

    if (fast) {
        unsigned short* ebf = (unsigned short*)d_ws;
        unsigned short* w2b = (unsigned short*)((char*)d_ws + EBF_BYTES);
        float* dvec = (float*)((char*)d_ws + EBF_BYTES + W2_BYTES);
        prep_all<<<dim3(32 + 32768 + 1024 + 256), dim3(256), 0, stream>>>(
            enc, attn_w, attn_b, hidden, ebf, w2b, dvec, out, 1);
        attn_gemm_fast<<<dim3(2048), dim3(256), 0, stream>>>(ebf, w2b, dvec, v_w, out);
    } else {
        unsigned short* w2b = (unsigned short*)d_ws;
        float* dvec = (float*)((char*)d_ws + W2_BYTES);
        prep_all<<<dim3(32 + 1024 + 256), dim3(256), 0, stream>>>(
            enc, attn_w, attn_b, hidden, nullptr, w2b, dvec, out, 0);
        attn_gemm_fb<<<dim3(2048), dim3(256), 0, stream>>>(enc, w2b, dvec, v_w, out);
    }
    softmax_k<<<dim3(1), dim3(1024), 0, stream>>>(out);
}